// Round 6
// baseline (229.657 us; speedup 1.0000x reference)
//
#include <hip/hip_runtime.h>
#include <hip/hip_bf16.h>
#include <math.h>

#define PROJ_EPSF 0.004f
#define MIN_NORMF 1e-15f
#define ATANH_EPSF 1e-5f
#define WEI_EPSF 1e-3f
#define LN2F 0.69314718055994531f

#define TT 1024
#define CC 768
#define HH 12
#define BBATCH 4

typedef unsigned long long ull;
typedef __attribute__((ext_vector_type(4))) float f32x4;
typedef __attribute__((ext_vector_type(8))) short bf16x8;

#define MFMA(a, b, c) __builtin_amdgcn_mfma_f32_16x16x32_bf16(a, b, c, 0, 0, 0)

static __device__ __forceinline__ uint cvtpk(float a, float b) {
    uint r;
    asm("v_cvt_pk_bf16_f32 %0, %1, %2" : "=v"(r) : "v"(a), "v"(b));
    return r;
}
static __device__ __forceinline__ ushort f2bf(float f) {
    uint u = __float_as_uint(f);
    u += 0x7fffu + ((u >> 16) & 1u);
    return (ushort)(u >> 16);
}
static __device__ __forceinline__ float bf2f(ushort h) {
    return __uint_as_float(((uint)h) << 16);
}
static __device__ __forceinline__ void split4(const float4& f, ull& hp, ull& lp) {
    uint h01 = cvtpk(f.x, f.y), h23 = cvtpk(f.z, f.w);
    float r0 = f.x - __uint_as_float(h01 << 16);
    float r1 = f.y - __uint_as_float(h01 & 0xffff0000u);
    float r2 = f.z - __uint_as_float(h23 << 16);
    float r3 = f.w - __uint_as_float(h23 & 0xffff0000u);
    uint l01 = cvtpk(r0, r1), l23 = cvtpk(r2, r3);
    hp = ((ull)h23 << 32) | h01;
    lp = ((ull)l23 << 32) | l01;
}

// ---------------- prep: f32 -> bf16 hi/lo planes ----------------
__global__ __launch_bounds__(256) void wprep(const float* __restrict__ W,
                                             ushort* __restrict__ Wh,
                                             ushort* __restrict__ Wl, int n4) {
    int i = blockIdx.x * 256 + threadIdx.x;
    if (i < n4) {
        float4 f = ((const float4*)W)[i];
        ull hp, lp;
        split4(f, hp, lp);
        ((ull*)Wh)[i] = hp;
        ((ull*)Wl)[i] = lp;
    }
}

// ---------------- fused QKV GEMM + Poincare projection + layout ----------------
template <bool PS>
__global__ __launch_bounds__(256) void gemm_qkv(
        const float* __restrict__ xf, const ushort* __restrict__ xhp,
        const ushort* __restrict__ xlp, const ushort* __restrict__ Wh,
        const ushort* __restrict__ Wl, const float* __restrict__ kcurv,
        ushort* __restrict__ qh, ushort* __restrict__ ql,
        ushort* __restrict__ kh, ushort* __restrict__ kl,
        ushort* __restrict__ vT, float* __restrict__ x2g,
        float* __restrict__ y2g) {
    __shared__ ushort Ah[128 * 40], Al[128 * 40], Bh[128 * 40], Bl[128 * 40];
    const int tid = threadIdx.x, lane = tid & 63, wv = tid >> 6;
    const int wr = wv >> 1, wc = wv & 1, lr = lane & 15, lg = lane >> 4;
    const int m0 = blockIdx.y * 128, n0 = blockIdx.x * 128;
    const bool isV = (n0 >= 2 * CC);
    const int srow = tid >> 1, sk0 = (tid & 1) * 16;
    const float* Ap = xf + (size_t)(m0 + srow) * CC + sk0;
    const ushort* Axh = xhp + (size_t)(m0 + srow) * CC + sk0;
    const ushort* Axl = xlp + (size_t)(m0 + srow) * CC + sk0;
    const ushort* Bhp = Wh + (size_t)(n0 + srow) * CC + sk0;
    const ushort* Blp = Wl + (size_t)(n0 + srow) * CC + sk0;

    f32x4 acc[4][4] = {};
    float4 av[4];
    bf16x8 ahv[2], alv[2], bhv[2], blv[2];
    if constexpr (PS) {
        ahv[0] = *(const bf16x8*)(Axh);
        ahv[1] = *(const bf16x8*)(Axh + 8);
        if (!isV) {
            alv[0] = *(const bf16x8*)(Axl);
            alv[1] = *(const bf16x8*)(Axl + 8);
        }
    } else {
#pragma unroll
        for (int q = 0; q < 4; ++q) av[q] = *(const float4*)(Ap + 4 * q);
    }
    bhv[0] = *(const bf16x8*)(Bhp);
    bhv[1] = *(const bf16x8*)(Bhp + 8);
    if (!isV) {
        blv[0] = *(const bf16x8*)(Blp);
        blv[1] = *(const bf16x8*)(Blp + 8);
    }

    for (int kk = 0; kk < CC; kk += 32) {
        __syncthreads();
        if constexpr (PS) {
            *(bf16x8*)&Ah[srow * 40 + sk0] = ahv[0];
            *(bf16x8*)&Ah[srow * 40 + sk0 + 8] = ahv[1];
            if (!isV) {
                *(bf16x8*)&Al[srow * 40 + sk0] = alv[0];
                *(bf16x8*)&Al[srow * 40 + sk0 + 8] = alv[1];
            }
        } else {
#pragma unroll
            for (int q = 0; q < 4; ++q) {
                ull hp, lp;
                split4(av[q], hp, lp);
                *(ull*)&Ah[srow * 40 + sk0 + 4 * q] = hp;
                if (!isV) *(ull*)&Al[srow * 40 + sk0 + 4 * q] = lp;
            }
        }
        *(bf16x8*)&Bh[srow * 40 + sk0] = bhv[0];
        *(bf16x8*)&Bh[srow * 40 + sk0 + 8] = bhv[1];
        if (!isV) {
            *(bf16x8*)&Bl[srow * 40 + sk0] = blv[0];
            *(bf16x8*)&Bl[srow * 40 + sk0 + 8] = blv[1];
        }
        __syncthreads();
        if (kk + 32 < CC) {
            if constexpr (PS) {
                ahv[0] = *(const bf16x8*)(Axh + kk + 32);
                ahv[1] = *(const bf16x8*)(Axh + kk + 40);
                if (!isV) {
                    alv[0] = *(const bf16x8*)(Axl + kk + 32);
                    alv[1] = *(const bf16x8*)(Axl + kk + 40);
                }
            } else {
#pragma unroll
                for (int q = 0; q < 4; ++q)
                    av[q] = *(const float4*)(Ap + kk + 32 + 4 * q);
            }
            bhv[0] = *(const bf16x8*)(Bhp + kk + 32);
            bhv[1] = *(const bf16x8*)(Bhp + kk + 40);
            if (!isV) {
                blv[0] = *(const bf16x8*)(Blp + kk + 32);
                blv[1] = *(const bf16x8*)(Blp + kk + 40);
            }
        }
        if (!isV) {
            bf16x8 a_h[4], a_l[4];
#pragma unroll
            for (int m = 0; m < 4; ++m) {
                const int off = (wr * 64 + m * 16 + lr) * 40 + lg * 8;
                a_h[m] = *(const bf16x8*)&Ah[off];
                a_l[m] = *(const bf16x8*)&Al[off];
            }
#pragma unroll
            for (int n = 0; n < 4; ++n) {
                const int off = (wc * 64 + n * 16 + lr) * 40 + lg * 8;
                bf16x8 b_h = *(const bf16x8*)&Bh[off];
                bf16x8 b_l = *(const bf16x8*)&Bl[off];
#pragma unroll
                for (int m = 0; m < 4; ++m) {
                    acc[m][n] = MFMA(a_h[m], b_h, acc[m][n]);
                    acc[m][n] = MFMA(a_h[m], b_l, acc[m][n]);
                    acc[m][n] = MFMA(a_l[m], b_h, acc[m][n]);
                }
            }
        } else {
            bf16x8 a_h[4], b_h[4];
#pragma unroll
            for (int m = 0; m < 4; ++m)
                a_h[m] = *(const bf16x8*)&Ah[(wr * 64 + m * 16 + lr) * 40 + lg * 8];
#pragma unroll
            for (int n = 0; n < 4; ++n)
                b_h[n] = *(const bf16x8*)&Bh[(wc * 64 + n * 16 + lr) * 40 + lg * 8];
#pragma unroll
            for (int n = 0; n < 4; ++n)
#pragma unroll
                for (int m = 0; m < 4; ++m)
                    acc[n][m] = MFMA(b_h[n], a_h[m], acc[n][m]);
        }
    }
    // ---- epilogue ----
    if (isV) {
        const int hd = (n0 - 2 * CC) / 64 + wc;
#pragma unroll
        for (int n = 0; n < 4; ++n)
#pragma unroll
            for (int m = 0; m < 4; ++m)
#pragma unroll
                for (int r = 0; r < 4; ++r) {
                    const int dl = n * 16 + lg * 4 + r;
                    const int tok = m0 + wr * 64 + m * 16 + lr;
                    vT[(size_t)(hd * 64 + dl) * 4096 + tok] = f2bf(acc[n][m][r]);
                }
    } else {
        const bool isQ = (n0 < CC);
        const int hd = (isQ ? n0 : n0 - CC) / 64 + wc;
        ushort* ph = isQ ? qh : kh;
        ushort* pl = isQ ? ql : kl;
        float* sg = isQ ? x2g : y2g;
        const float kcv = kcurv[hd];
        const float mxn = (1.0f - PROJ_EPSF) / sqrtf(kcv);
        const float mxn2 = mxn * mxn;
#pragma unroll
        for (int m = 0; m < 4; ++m)
#pragma unroll
            for (int r = 0; r < 4; ++r) {
                float s = 0.f;
#pragma unroll
                for (int n = 0; n < 4; ++n) s = fmaf(acc[m][n][r], acc[m][n][r], s);
                s += __shfl_xor(s, 1);
                s += __shfl_xor(s, 2);
                s += __shfl_xor(s, 4);
                s += __shfl_xor(s, 8);
                float scale = 1.0f, x2v = s;
                if (s > mxn2) {
                    scale = mxn * __builtin_amdgcn_rcpf(sqrtf(s));
                    x2v = s * scale * scale;
                }
                const int tok = m0 + wr * 64 + m * 16 + lg * 4 + r;
                const size_t rowb = (size_t)tok * CC + (isQ ? n0 : n0 - CC) + wc * 64;
#pragma unroll
                for (int n = 0; n < 4; ++n) {
                    const float v = acc[m][n][r] * scale;
                    const ushort hb = f2bf(v);
                    ph[rowb + n * 16 + lr] = hb;
                    pl[rowb + n * 16 + lr] = f2bf(v - bf2f(hb));
                }
                if (lr == 0)
                    sg[(size_t)((tok >> 10) * HH + hd) * TT + (tok & 1023)] = x2v;
            }
    }
}

// ---------------- 4-way split-j fused hyperbolic attention ----------------
// Block = one 16-row group (rg), 4 waves; wave w handles jt = w, w+4, ...
// Streamed K groups (2-ahead prefetch), transform overlaps MFMA+loads.
__global__ __launch_bounds__(256) void hyp_attn(
        const ushort* __restrict__ qh, const ushort* __restrict__ ql,
        const ushort* __restrict__ kh, const ushort* __restrict__ kl,
        const ushort* __restrict__ vT, const float* __restrict__ x2g,
        const float* __restrict__ y2g, const float* __restrict__ kcurv,
        ushort* __restrict__ yh, ushort* __restrict__ yl) {
    const int rg = 63 - (int)blockIdx.x;    // long blocks first
    const int h = blockIdx.y, b = blockIdx.z;
    const int tid = threadIdx.x, lane = tid & 63, wv = tid >> 6;
    const int lr = lane & 15, lg = lane >> 4;
    const int rgq = rg >> 2;
    const int bh = b * HH + h;

    __shared__ ushort wt[4][16 * 72];
    __shared__ float cmb[3][16][65];
    __shared__ float dcmb[3][16];
    ushort* wtw = wt[wv];

    const float kc = kcurv[h];
    const float sk = sqrtf(kc);
    const float distc = LN2F / sk;
    const float d2c = distc * distc;
    const float twokc = 2.0f * kc;
    const float cA = 1.0f - ATANH_EPSF;

    // Q fragments + per-row x2 (same for all 4 waves)
    const size_t qrb = (size_t)(b * TT + rg * 16 + lr) * CC + h * 64 + lg * 8;
    const bf16x8 qH0 = *(const bf16x8*)(qh + qrb), qH1 = *(const bf16x8*)(qh + qrb + 32);
    const bf16x8 qL0 = *(const bf16x8*)(ql + qrb), qL1 = *(const bf16x8*)(ql + qrb + 32);
    const float4 x2v = *(const float4*)&x2g[(size_t)bh * TT + rg * 16 + lg * 4];
    const float x2a[4] = { x2v.x, x2v.y, x2v.z, x2v.w };
    float kx2[4], Bc[4], Bc2[4];
#pragma unroll
    for (int r = 0; r < 4; ++r) {
        kx2[r] = kc * x2a[r];
        Bc[r] = 1.0f - kx2[r];
        Bc2[r] = Bc[r] * Bc[r];
    }

    f32x4 pv0 = {}, pv1 = {}, pv2 = {}, pv3 = {};
    float wsum[4] = {};

#define TRANSF(NN, SA, Y2R)                                                        \
    {                                                                              \
        const float ky2 = kc * (Y2R);                                              \
        const float p1 = 1.0f + ky2;                                               \
        const int jg = j0 + NN * 16 + lr;                                          \
        _Pragma("unroll") for (int r = 0; r < 4; ++r) {                            \
            const float xy = SA[r];                                                \
            const float t2 = twokc * xy;                                           \
            const float Aa = p1 - t2;                                              \
            const float dn = fmaxf(fmaf(kx2[r], ky2, 1.0f) - t2, MIN_NORMF);       \
            const float ABxy = Aa * (Bc[r] * xy);                                  \
            const float c1 = fmaf(Bc2[r], (Y2R), -2.0f * ABxy);                    \
            const float num2 = fmaf(Aa * Aa, x2a[r], c1);                          \
            const float s = sqrtf(fmaxf(num2, MIN_NORMF));                         \
            const float sm = fminf(sk * s, cA * dn);                               \
            const float L = __builtin_amdgcn_logf((dn + sm) *                      \
                                __builtin_amdgcn_rcpf(dn - sm));                   \
            float w = __builtin_amdgcn_rcpf(fmaf(L * L, d2c, WEI_EPSF));           \
            if (mk && (jg > rg * 16 + lg * 4 + r)) w = 0.0f;                       \
            wtw[(lg * 4 + r) * 72 + NN * 16 + lr] = f2bf(w);                       \
            wsum[r] += w;                                                          \
        }                                                                          \
    }

#define LOADG(i)                                                                   \
    kH##i[0] = *(const bf16x8*)(kh + kbase + i * 16 * CC);                         \
    kH##i[1] = *(const bf16x8*)(kh + kbase + i * 16 * CC + 32);                    \
    kL##i[0] = *(const bf16x8*)(kl + kbase + i * 16 * CC);                         \
    kL##i[1] = *(const bf16x8*)(kl + kbase + i * 16 * CC + 32);

#define MMG(SA, KH, KL)                                                            \
    SA = MFMA(qH0, KH[0], SA); SA = MFMA(qH0, KL[0], SA); SA = MFMA(qL0, KH[0], SA); \
    SA = MFMA(qH1, KH[1], SA); SA = MFMA(qH1, KL[1], SA); SA = MFMA(qL1, KH[1], SA);

    for (int jt = wv; jt <= rgq; jt += 4) {
        const int j0 = jt * 64;
        const bool mk = (jt == rgq);
        const size_t kbase = (size_t)(b * TT + j0 + lr) * CC + h * 64 + lg * 8;
        const size_t y2b = (size_t)bh * TT + j0 + lr;
        bf16x8 kH0[2], kL0[2], kH1[2], kL1[2], kH2[2], kL2[2], kH3[2], kL3[2];
        LOADG(0)
        LOADG(1)
        const float y20 = y2g[y2b], y21 = y2g[y2b + 16];
        const float y22 = y2g[y2b + 32], y23 = y2g[y2b + 48];
        f32x4 s0 = {}, s1 = {}, s2 = {}, s3 = {};
        MMG(s0, kH0, kL0)
        LOADG(2)
        TRANSF(0, s0, y20)
        MMG(s1, kH1, kL1)
        LOADG(3)
        TRANSF(1, s1, y21)
        MMG(s2, kH2, kL2)
        TRANSF(2, s2, y22)
        MMG(s3, kH3, kL3)
        // V fragments (in flight during last transform)
        bf16x8 vF[4][2];
#pragma unroll
        for (int n = 0; n < 4; ++n) {
            const size_t vb = (size_t)(h * 64 + n * 16 + lr) * 4096 + b * TT + j0 + lg * 8;
            vF[n][0] = *(const bf16x8*)(vT + vb);
            vF[n][1] = *(const bf16x8*)(vT + vb + 32);
        }
        TRANSF(3, s3, y23)
        // ---- PV ----
        bf16x8 pw0 = *(const bf16x8*)&wtw[lr * 72 + lg * 8];
        bf16x8 pw1 = *(const bf16x8*)&wtw[lr * 72 + 32 + lg * 8];
        pv0 = MFMA(pw0, vF[0][0], pv0); pv0 = MFMA(pw1, vF[0][1], pv0);
        pv1 = MFMA(pw0, vF[1][0], pv1); pv1 = MFMA(pw1, vF[1][1], pv1);
        pv2 = MFMA(pw0, vF[2][0], pv2); pv2 = MFMA(pw1, vF[2][1], pv2);
        pv3 = MFMA(pw0, vF[3][0], pv3); pv3 = MFMA(pw1, vF[3][1], pv3);
    }

    // ---- reduce den over lr lanes ----
    float den[4];
#pragma unroll
    for (int r = 0; r < 4; ++r) {
        float s = wsum[r];
        s += __shfl_xor(s, 1);
        s += __shfl_xor(s, 2);
        s += __shfl_xor(s, 4);
        s += __shfl_xor(s, 8);
        den[r] = s;
    }
    // ---- combine partials across the 4 waves ----
    if (wv > 0) {
#pragma unroll
        for (int r = 0; r < 4; ++r) {
            cmb[wv - 1][lg * 4 + r][0 * 16 + lr] = pv0[r];
            cmb[wv - 1][lg * 4 + r][1 * 16 + lr] = pv1[r];
            cmb[wv - 1][lg * 4 + r][2 * 16 + lr] = pv2[r];
            cmb[wv - 1][lg * 4 + r][3 * 16 + lr] = pv3[r];
        }
        if (lr == 0)
#pragma unroll
            for (int r = 0; r < 4; ++r) dcmb[wv - 1][lg * 4 + r] = den[r];
    }
    __syncthreads();
    if (wv == 0) {
        f32x4* pvp[4] = { &pv0, &pv1, &pv2, &pv3 };
#pragma unroll
        for (int r = 0; r < 4; ++r) {
            const int il = lg * 4 + r;
            const float dt = den[r] + dcmb[0][il] + dcmb[1][il] + dcmb[2][il];
            const float iv = __builtin_amdgcn_rcpf(dt);
            const size_t rowb = (size_t)(b * TT + rg * 16 + il) * CC + h * 64;
#pragma unroll
            for (int n = 0; n < 4; ++n) {
                const float val = ((*pvp[n])[r] + cmb[0][il][n * 16 + lr] +
                                   cmb[1][il][n * 16 + lr] + cmb[2][il][n * 16 + lr]) * iv;
                const ushort hb = f2bf(val);
                yh[rowb + n * 16 + lr] = hb;
                yl[rowb + n * 16 + lr] = f2bf(val - bf2f(hb));
            }
        }
    }
#undef TRANSF
#undef LOADG
#undef MMG
}

// ---------------- output GEMM: out = y @ Wproj^T (pre-split A and B) ----------------
__global__ __launch_bounds__(256) void gemm_out(const ushort* __restrict__ Ahp,
                                                const ushort* __restrict__ Alp,
                                                const ushort* __restrict__ Wh,
                                                const ushort* __restrict__ Wl,
                                                float* __restrict__ C) {
    __shared__ ushort Ah[128 * 40], Al[128 * 40], Bh[128 * 40], Bl[128 * 40];
    const int tid = threadIdx.x, lane = tid & 63, wv = tid >> 6;
    const int wr = wv >> 1, wc = wv & 1, lr = lane & 15, lg = lane >> 4;
    const int m0 = blockIdx.y * 128, n0 = blockIdx.x * 128;
    const int srow = tid >> 1, sk0 = (tid & 1) * 16;
    const ushort* Ahq = Ahp + (size_t)(m0 + srow) * CC + sk0;
    const ushort* Alq = Alp + (size_t)(m0 + srow) * CC + sk0;
    const ushort* Bhp = Wh + (size_t)(n0 + srow) * CC + sk0;
    const ushort* Blp = Wl + (size_t)(n0 + srow) * CC + sk0;

    f32x4 acc[4][4] = {};
    bf16x8 ahv[2], alv[2], bhv[2], blv[2];
    ahv[0] = *(const bf16x8*)(Ahq);      ahv[1] = *(const bf16x8*)(Ahq + 8);
    alv[0] = *(const bf16x8*)(Alq);      alv[1] = *(const bf16x8*)(Alq + 8);
    bhv[0] = *(const bf16x8*)(Bhp);      bhv[1] = *(const bf16x8*)(Bhp + 8);
    blv[0] = *(const bf16x8*)(Blp);      blv[1] = *(const bf16x8*)(Blp + 8);

    for (int kk = 0; kk < CC; kk += 32) {
        __syncthreads();
        *(bf16x8*)&Ah[srow * 40 + sk0] = ahv[0];
        *(bf16x8*)&Ah[srow * 40 + sk0 + 8] = ahv[1];
        *(bf16x8*)&Al[srow * 40 + sk0] = alv[0];
        *(bf16x8*)&Al[srow * 40 + sk0 + 8] = alv[1];
        *(bf16x8*)&Bh[srow * 40 + sk0] = bhv[0];
        *(bf16x8*)&Bh[srow * 40 + sk0 + 8] = bhv[1];
        *(bf16x8*)&Bl[srow * 40 + sk0] = blv[0];
        *(bf16x8*)&Bl[srow * 40 + sk0 + 8] = blv[1];
        __syncthreads();
        if (kk + 32 < CC) {
            ahv[0] = *(const bf16x8*)(Ahq + kk + 32);
            ahv[1] = *(const bf16x8*)(Ahq + kk + 40);
            alv[0] = *(const bf16x8*)(Alq + kk + 32);
            alv[1] = *(const bf16x8*)(Alq + kk + 40);
            bhv[0] = *(const bf16x8*)(Bhp + kk + 32);
            bhv[1] = *(const bf16x8*)(Bhp + kk + 40);
            blv[0] = *(const bf16x8*)(Blp + kk + 32);
            blv[1] = *(const bf16x8*)(Blp + kk + 40);
        }
        bf16x8 a_h[4], a_l[4];
#pragma unroll
        for (int m = 0; m < 4; ++m) {
            const int off = (wr * 64 + m * 16 + lr) * 40 + lg * 8;
            a_h[m] = *(const bf16x8*)&Ah[off];
            a_l[m] = *(const bf16x8*)&Al[off];
        }
#pragma unroll
        for (int n = 0; n < 4; ++n) {
            const int off = (wc * 64 + n * 16 + lr) * 40 + lg * 8;
            bf16x8 b_h = *(const bf16x8*)&Bh[off];
            bf16x8 b_l = *(const bf16x8*)&Bl[off];
#pragma unroll
            for (int m = 0; m < 4; ++m) {
                acc[m][n] = MFMA(a_h[m], b_h, acc[m][n]);
                acc[m][n] = MFMA(a_h[m], b_l, acc[m][n]);
                acc[m][n] = MFMA(a_l[m], b_h, acc[m][n]);
            }
        }
    }
#pragma unroll
    for (int m = 0; m < 4; ++m)
#pragma unroll
        for (int n = 0; n < 4; ++n)
#pragma unroll
            for (int r = 0; r < 4; ++r)
                C[(size_t)(m0 + wr * 64 + m * 16 + lg * 4 + r) * CC + n0 + wc * 64 + n * 16 + lr] =
                    acc[m][n][r];
}

extern "C" void kernel_launch(void* const* d_in, const int* in_sizes, int n_in,
                              void* d_out, int out_size, void* d_ws, size_t ws_size,
                              hipStream_t stream) {
    const float* x     = (const float*)d_in[0];
    const float* Wqkv  = (const float*)d_in[1];
    const float* Wproj = (const float*)d_in[2];
    const float* kcurv = (const float*)d_in[3];
    float* out = (float*)d_out;

    const size_t PL = (size_t)4096 * CC;
    char* w = (char*)d_ws;
    const bool ps = ws_size >= 53870592ULL;

    ushort *xh, *xl, *qh, *ql, *kh, *kl, *vT, *Wqh, *Wql, *Wph, *Wpl, *yh, *yl;
    float *x2g, *y2g;
    if (ps) {
        xh = (ushort*)w;          xl = xh + PL;     // reused as yh/yl later
        qh = xl + PL;  ql = qh + PL;  kh = ql + PL;  kl = kh + PL;  vT = kl + PL;
        x2g = (float*)(vT + PL);  y2g = x2g + 48 * TT;
        Wqh = (ushort*)(y2g + 48 * TT);  Wql = Wqh + (size_t)2304 * CC;
        Wph = Wql + (size_t)2304 * CC;   Wpl = Wph + (size_t)CC * CC;
        yh = (ushort*)w;  yl = yh + PL;
    } else {
        Wqh = (ushort*)w;  Wql = Wqh + (size_t)2304 * CC;
        yh = (ushort*)w;   yl = yh + PL;
        qh = (ushort*)(w + 2 * PL * 2);
        ql = qh + PL;  kh = ql + PL;  kl = kh + PL;  vT = kl + PL;
        Wph = vT + PL;  Wpl = Wph + (size_t)CC * CC;
        x2g = (float*)(Wpl + (size_t)CC * CC);  y2g = x2g + 48 * TT;
        xh = xl = nullptr;
    }

    wprep<<<2304 * CC / 4 / 256, 256, 0, stream>>>(Wqkv, Wqh, Wql, 2304 * CC / 4);
    wprep<<<CC * CC / 4 / 256, 256, 0, stream>>>(Wproj, Wph, Wpl, CC * CC / 4);
    if (ps) {
        wprep<<<4096 * CC / 4 / 256, 256, 0, stream>>>(x, xh, xl, 4096 * CC / 4);
        gemm_qkv<true><<<dim3(18, 32), 256, 0, stream>>>(x, xh, xl, Wqh, Wql, kcurv,
                                                         qh, ql, kh, kl, vT, x2g, y2g);
    } else {
        gemm_qkv<false><<<dim3(18, 32), 256, 0, stream>>>(x, nullptr, nullptr, Wqh, Wql,
                                                          kcurv, qh, ql, kh, kl, vT, x2g, y2g);
    }
    hyp_attn<<<dim3(64, HH, BBATCH), 256, 0, stream>>>(qh, ql, kh, kl, vT,
                                                       x2g, y2g, kcurv, yh, yl);
    gemm_out<<<dim3(6, 32), 256, 0, stream>>>(yh, yl, Wph, Wpl, out);
}

// Round 7
// 203.857 us; speedup vs baseline: 1.1266x; 1.1266x over previous
//
#include <hip/hip_runtime.h>
#include <hip/hip_bf16.h>
#include <math.h>

#define PROJ_EPSF 0.004f
#define MIN_NORMF 1e-15f
#define ATANH_EPSF 1e-5f
#define WEI_EPSF 1e-3f
#define LN2F 0.69314718055994531f

#define TT 1024
#define CC 768
#define HH 12
#define BBATCH 4

typedef unsigned long long ull;
typedef __attribute__((ext_vector_type(4))) float f32x4;
typedef __attribute__((ext_vector_type(8))) short bf16x8;

#define MFMA(a, b, c) __builtin_amdgcn_mfma_f32_16x16x32_bf16(a, b, c, 0, 0, 0)

static __device__ __forceinline__ uint cvtpk(float a, float b) {
    uint r;
    asm("v_cvt_pk_bf16_f32 %0, %1, %2" : "=v"(r) : "v"(a), "v"(b));
    return r;
}
static __device__ __forceinline__ ushort f2bf(float f) {
    uint u = __float_as_uint(f);
    u += 0x7fffu + ((u >> 16) & 1u);
    return (ushort)(u >> 16);
}
static __device__ __forceinline__ float bf2f(ushort h) {
    return __uint_as_float(((uint)h) << 16);
}
static __device__ __forceinline__ void split4(const float4& f, ull& hp, ull& lp) {
    uint h01 = cvtpk(f.x, f.y), h23 = cvtpk(f.z, f.w);
    float r0 = f.x - __uint_as_float(h01 << 16);
    float r1 = f.y - __uint_as_float(h01 & 0xffff0000u);
    float r2 = f.z - __uint_as_float(h23 << 16);
    float r3 = f.w - __uint_as_float(h23 & 0xffff0000u);
    uint l01 = cvtpk(r0, r1), l23 = cvtpk(r2, r3);
    hp = ((ull)h23 << 32) | h01;
    lp = ((ull)l23 << 32) | l01;
}

// ---------------- prep: f32 -> bf16 hi/lo planes ----------------
__global__ __launch_bounds__(256) void wprep(const float* __restrict__ W,
                                             ushort* __restrict__ Wh,
                                             ushort* __restrict__ Wl, int n4) {
    int i = blockIdx.x * 256 + threadIdx.x;
    if (i < n4) {
        float4 f = ((const float4*)W)[i];
        ull hp, lp;
        split4(f, hp, lp);
        ((ull*)Wh)[i] = hp;
        ((ull*)Wl)[i] = lp;
    }
}

// ---------------- fused QKV GEMM + Poincare projection + layout ----------------
template <bool PS>
__global__ __launch_bounds__(256) void gemm_qkv(
        const float* __restrict__ xf, const ushort* __restrict__ xhp,
        const ushort* __restrict__ xlp, const ushort* __restrict__ Wh,
        const ushort* __restrict__ Wl, const float* __restrict__ kcurv,
        ushort* __restrict__ qh, ushort* __restrict__ ql,
        ushort* __restrict__ kh, ushort* __restrict__ kl,
        ushort* __restrict__ vT, float* __restrict__ x2g,
        float* __restrict__ y2g) {
    __shared__ ushort Ah[128 * 40], Al[128 * 40], Bh[128 * 40], Bl[128 * 40];
    const int tid = threadIdx.x, lane = tid & 63, wv = tid >> 6;
    const int wr = wv >> 1, wc = wv & 1, lr = lane & 15, lg = lane >> 4;
    const int m0 = blockIdx.y * 128, n0 = blockIdx.x * 128;
    const bool isV = (n0 >= 2 * CC);
    const int srow = tid >> 1, sk0 = (tid & 1) * 16;
    const float* Ap = xf + (size_t)(m0 + srow) * CC + sk0;
    const ushort* Axh = xhp + (size_t)(m0 + srow) * CC + sk0;
    const ushort* Axl = xlp + (size_t)(m0 + srow) * CC + sk0;
    const ushort* Bhp = Wh + (size_t)(n0 + srow) * CC + sk0;
    const ushort* Blp = Wl + (size_t)(n0 + srow) * CC + sk0;

    f32x4 acc[4][4] = {};
    float4 av[4];
    bf16x8 ahv[2], alv[2], bhv[2], blv[2];
    if constexpr (PS) {
        ahv[0] = *(const bf16x8*)(Axh);
        ahv[1] = *(const bf16x8*)(Axh + 8);
        if (!isV) {
            alv[0] = *(const bf16x8*)(Axl);
            alv[1] = *(const bf16x8*)(Axl + 8);
        }
    } else {
#pragma unroll
        for (int q = 0; q < 4; ++q) av[q] = *(const float4*)(Ap + 4 * q);
    }
    bhv[0] = *(const bf16x8*)(Bhp);
    bhv[1] = *(const bf16x8*)(Bhp + 8);
    if (!isV) {
        blv[0] = *(const bf16x8*)(Blp);
        blv[1] = *(const bf16x8*)(Blp + 8);
    }

    for (int kk = 0; kk < CC; kk += 32) {
        __syncthreads();
        if constexpr (PS) {
            *(bf16x8*)&Ah[srow * 40 + sk0] = ahv[0];
            *(bf16x8*)&Ah[srow * 40 + sk0 + 8] = ahv[1];
            if (!isV) {
                *(bf16x8*)&Al[srow * 40 + sk0] = alv[0];
                *(bf16x8*)&Al[srow * 40 + sk0 + 8] = alv[1];
            }
        } else {
#pragma unroll
            for (int q = 0; q < 4; ++q) {
                ull hp, lp;
                split4(av[q], hp, lp);
                *(ull*)&Ah[srow * 40 + sk0 + 4 * q] = hp;
                if (!isV) *(ull*)&Al[srow * 40 + sk0 + 4 * q] = lp;
            }
        }
        *(bf16x8*)&Bh[srow * 40 + sk0] = bhv[0];
        *(bf16x8*)&Bh[srow * 40 + sk0 + 8] = bhv[1];
        if (!isV) {
            *(bf16x8*)&Bl[srow * 40 + sk0] = blv[0];
            *(bf16x8*)&Bl[srow * 40 + sk0 + 8] = blv[1];
        }
        __syncthreads();
        if (kk + 32 < CC) {
            if constexpr (PS) {
                ahv[0] = *(const bf16x8*)(Axh + kk + 32);
                ahv[1] = *(const bf16x8*)(Axh + kk + 40);
                if (!isV) {
                    alv[0] = *(const bf16x8*)(Axl + kk + 32);
                    alv[1] = *(const bf16x8*)(Axl + kk + 40);
                }
            } else {
#pragma unroll
                for (int q = 0; q < 4; ++q)
                    av[q] = *(const float4*)(Ap + kk + 32 + 4 * q);
            }
            bhv[0] = *(const bf16x8*)(Bhp + kk + 32);
            bhv[1] = *(const bf16x8*)(Bhp + kk + 40);
            if (!isV) {
                blv[0] = *(const bf16x8*)(Blp + kk + 32);
                blv[1] = *(const bf16x8*)(Blp + kk + 40);
            }
        }
        if (!isV) {
            bf16x8 a_h[4], a_l[4];
#pragma unroll
            for (int m = 0; m < 4; ++m) {
                const int off = (wr * 64 + m * 16 + lr) * 40 + lg * 8;
                a_h[m] = *(const bf16x8*)&Ah[off];
                a_l[m] = *(const bf16x8*)&Al[off];
            }
#pragma unroll
            for (int n = 0; n < 4; ++n) {
                const int off = (wc * 64 + n * 16 + lr) * 40 + lg * 8;
                bf16x8 b_h = *(const bf16x8*)&Bh[off];
                bf16x8 b_l = *(const bf16x8*)&Bl[off];
#pragma unroll
                for (int m = 0; m < 4; ++m) {
                    acc[m][n] = MFMA(a_h[m], b_h, acc[m][n]);
                    acc[m][n] = MFMA(a_h[m], b_l, acc[m][n]);
                    acc[m][n] = MFMA(a_l[m], b_h, acc[m][n]);
                }
            }
        } else {
            bf16x8 a_h[4], b_h[4];
#pragma unroll
            for (int m = 0; m < 4; ++m)
                a_h[m] = *(const bf16x8*)&Ah[(wr * 64 + m * 16 + lr) * 40 + lg * 8];
#pragma unroll
            for (int n = 0; n < 4; ++n)
                b_h[n] = *(const bf16x8*)&Bh[(wc * 64 + n * 16 + lr) * 40 + lg * 8];
#pragma unroll
            for (int n = 0; n < 4; ++n)
#pragma unroll
                for (int m = 0; m < 4; ++m)
                    acc[n][m] = MFMA(b_h[n], a_h[m], acc[n][m]);
        }
    }
    // ---- epilogue ----
    if (isV) {
        const int hd = (n0 - 2 * CC) / 64 + wc;
#pragma unroll
        for (int n = 0; n < 4; ++n)
#pragma unroll
            for (int m = 0; m < 4; ++m)
#pragma unroll
                for (int r = 0; r < 4; ++r) {
                    const int dl = n * 16 + lg * 4 + r;
                    const int tok = m0 + wr * 64 + m * 16 + lr;
                    vT[(size_t)(hd * 64 + dl) * 4096 + tok] = f2bf(acc[n][m][r]);
                }
    } else {
        const bool isQ = (n0 < CC);
        const int hd = (isQ ? n0 : n0 - CC) / 64 + wc;
        ushort* ph = isQ ? qh : kh;
        ushort* pl = isQ ? ql : kl;
        float* sg = isQ ? x2g : y2g;
        const float kcv = kcurv[hd];
        const float mxn = (1.0f - PROJ_EPSF) / sqrtf(kcv);
        const float mxn2 = mxn * mxn;
#pragma unroll
        for (int m = 0; m < 4; ++m)
#pragma unroll
            for (int r = 0; r < 4; ++r) {
                float s = 0.f;
#pragma unroll
                for (int n = 0; n < 4; ++n) s = fmaf(acc[m][n][r], acc[m][n][r], s);
                s += __shfl_xor(s, 1);
                s += __shfl_xor(s, 2);
                s += __shfl_xor(s, 4);
                s += __shfl_xor(s, 8);
                float scale = 1.0f, x2v = s;
                if (s > mxn2) {
                    scale = mxn * __builtin_amdgcn_rcpf(sqrtf(s));
                    x2v = s * scale * scale;
                }
                const int tok = m0 + wr * 64 + m * 16 + lg * 4 + r;
                const size_t rowb = (size_t)tok * CC + (isQ ? n0 : n0 - CC) + wc * 64;
#pragma unroll
                for (int n = 0; n < 4; ++n) {
                    const float v = acc[m][n][r] * scale;
                    const ushort hb = f2bf(v);
                    ph[rowb + n * 16 + lr] = hb;
                    pl[rowb + n * 16 + lr] = f2bf(v - bf2f(hb));
                }
                if (lr == 0)
                    sg[(size_t)((tok >> 10) * HH + hd) * TT + (tok & 1023)] = x2v;
            }
    }
}

// ---------------- 4-way split-j attention, XCD-localized ----------------
// block i -> XCD i%8 (HW round-robin). All 64 row-groups of a (b,h) plane
// share one XCD -> K/V/q planes (~2 MB per XCD working set) stay L2-resident.
__global__ __launch_bounds__(256) void hyp_attn(
        const ushort* __restrict__ qh, const ushort* __restrict__ ql,
        const ushort* __restrict__ kh, const ushort* __restrict__ kl,
        const ushort* __restrict__ vT, const float* __restrict__ x2g,
        const float* __restrict__ y2g, const float* __restrict__ kcurv,
        ushort* __restrict__ yh, ushort* __restrict__ yl) {
    const int ib = (int)blockIdx.x;          // 0..3071
    const int xcd = ib & 7, t = ib >> 3;
    const int rg = 63 - (t & 63);            // long blocks first, per XCD
    const int bh = ((t >> 6) << 3) + xcd;    // 0..47, bh%8 == XCD id
    const int b = bh / HH, h = bh - b * HH;
    const int tid = threadIdx.x, lane = tid & 63, wv = tid >> 6;
    const int lr = lane & 15, lg = lane >> 4;
    const int rgq = rg >> 2;

    __shared__ ushort wt[4][16 * 72];
    __shared__ float cmb[3][16][65];
    __shared__ float dcmb[3][16];
    ushort* wtw = wt[wv];

    const float kc = kcurv[h];
    const float sk = sqrtf(kc);
    const float distc = LN2F / sk;
    const float d2c = distc * distc;
    const float twokc = 2.0f * kc;
    const float cA = 1.0f - ATANH_EPSF;

    // Q fragments + per-row x2 (same for all 4 waves)
    const size_t qrb = (size_t)(b * TT + rg * 16 + lr) * CC + h * 64 + lg * 8;
    const bf16x8 qH0 = *(const bf16x8*)(qh + qrb), qH1 = *(const bf16x8*)(qh + qrb + 32);
    const bf16x8 qL0 = *(const bf16x8*)(ql + qrb), qL1 = *(const bf16x8*)(ql + qrb + 32);
    const float4 x2v = *(const float4*)&x2g[(size_t)bh * TT + rg * 16 + lg * 4];
    const float x2a[4] = { x2v.x, x2v.y, x2v.z, x2v.w };
    float kx2[4], Bc[4], Bc2[4];
#pragma unroll
    for (int r = 0; r < 4; ++r) {
        kx2[r] = kc * x2a[r];
        Bc[r] = 1.0f - kx2[r];
        Bc2[r] = Bc[r] * Bc[r];
    }

    f32x4 pv0 = {}, pv1 = {}, pv2 = {}, pv3 = {};
    float wsum[4] = {};

#define TRANSF(NN, SA, Y2R)                                                        \
    {                                                                              \
        const float ky2 = kc * (Y2R);                                              \
        const float p1 = 1.0f + ky2;                                               \
        const int jg = j0 + NN * 16 + lr;                                          \
        _Pragma("unroll") for (int r = 0; r < 4; ++r) {                            \
            const float xy = SA[r];                                                \
            const float t2 = twokc * xy;                                           \
            const float Aa = p1 - t2;                                              \
            const float dn = fmaxf(fmaf(kx2[r], ky2, 1.0f) - t2, MIN_NORMF);       \
            const float ABxy = Aa * (Bc[r] * xy);                                  \
            const float c1 = fmaf(Bc2[r], (Y2R), -2.0f * ABxy);                    \
            const float num2 = fmaf(Aa * Aa, x2a[r], c1);                          \
            const float s = sqrtf(fmaxf(num2, MIN_NORMF));                         \
            const float sm = fminf(sk * s, cA * dn);                               \
            const float L = __builtin_amdgcn_logf((dn + sm) *                      \
                                __builtin_amdgcn_rcpf(dn - sm));                   \
            float w = __builtin_amdgcn_rcpf(fmaf(L * L, d2c, WEI_EPSF));           \
            if (mk && (jg > rg * 16 + lg * 4 + r)) w = 0.0f;                       \
            wtw[(lg * 4 + r) * 72 + NN * 16 + lr] = f2bf(w);                       \
            wsum[r] += w;                                                          \
        }                                                                          \
    }

#define LOADG2(KH, KL, BASE)                                                       \
    KH[0] = *(const bf16x8*)(kh + (BASE));                                         \
    KH[1] = *(const bf16x8*)(kh + (BASE) + 32);                                    \
    KL[0] = *(const bf16x8*)(kl + (BASE));                                         \
    KL[1] = *(const bf16x8*)(kl + (BASE) + 32);

#define MMG(SA, KH, KL)                                                            \
    SA = MFMA(qH0, KH[0], SA); SA = MFMA(qH0, KL[0], SA); SA = MFMA(qL0, KH[0], SA); \
    SA = MFMA(qH1, KH[1], SA); SA = MFMA(qH1, KL[1], SA); SA = MFMA(qL1, KH[1], SA);

    size_t kbase = (size_t)(b * TT + wv * 64 + lr) * CC + h * 64 + lg * 8;
    bf16x8 kH0[2], kL0[2], kH1[2], kL1[2], kH2[2], kL2[2], kH3[2], kL3[2];
    if (wv <= rgq) {
        LOADG2(kH0, kL0, kbase)
        LOADG2(kH1, kL1, kbase + 16 * CC)
    }

    for (int jt = wv; jt <= rgq; jt += 4) {
        const int j0 = jt * 64;
        const bool mk = (jt == rgq);
        const size_t y2b = (size_t)bh * TT + j0 + lr;
        const float y20 = y2g[y2b], y21 = y2g[y2b + 16];
        const float y22 = y2g[y2b + 32], y23 = y2g[y2b + 48];
        f32x4 s0 = {}, s1 = {}, s2 = {}, s3 = {};
        __builtin_amdgcn_s_setprio(1);
        MMG(s0, kH0, kL0)
        LOADG2(kH2, kL2, kbase + 32 * CC)
        TRANSF(0, s0, y20)
        MMG(s1, kH1, kL1)
        LOADG2(kH3, kL3, kbase + 48 * CC)
        TRANSF(1, s1, y21)
        MMG(s2, kH2, kL2)
        // V fragments: in flight during transforms 2,3
        bf16x8 vF[4][2];
#pragma unroll
        for (int n = 0; n < 4; ++n) {
            const size_t vb = (size_t)(h * 64 + n * 16 + lr) * 4096 + b * TT + j0 + lg * 8;
            vF[n][0] = *(const bf16x8*)(vT + vb);
            vF[n][1] = *(const bf16x8*)(vT + vb + 32);
        }
        TRANSF(2, s2, y22)
        MMG(s3, kH3, kL3)
        TRANSF(3, s3, y23)
        // prefetch next tile's first two K groups during PV
        kbase += (size_t)256 * CC;
        if (jt + 4 <= rgq) {
            LOADG2(kH0, kL0, kbase)
            LOADG2(kH1, kL1, kbase + 16 * CC)
        }
        // ---- PV ----
        bf16x8 pw0 = *(const bf16x8*)&wtw[lr * 72 + lg * 8];
        bf16x8 pw1 = *(const bf16x8*)&wtw[lr * 72 + 32 + lg * 8];
        pv0 = MFMA(pw0, vF[0][0], pv0); pv0 = MFMA(pw1, vF[0][1], pv0);
        pv1 = MFMA(pw0, vF[1][0], pv1); pv1 = MFMA(pw1, vF[1][1], pv1);
        pv2 = MFMA(pw0, vF[2][0], pv2); pv2 = MFMA(pw1, vF[2][1], pv2);
        pv3 = MFMA(pw0, vF[3][0], pv3); pv3 = MFMA(pw1, vF[3][1], pv3);
        __builtin_amdgcn_s_setprio(0);
    }

    // ---- reduce den over lr lanes ----
    float den[4];
#pragma unroll
    for (int r = 0; r < 4; ++r) {
        float s = wsum[r];
        s += __shfl_xor(s, 1);
        s += __shfl_xor(s, 2);
        s += __shfl_xor(s, 4);
        s += __shfl_xor(s, 8);
        den[r] = s;
    }
    // ---- combine partials across the 4 waves ----
    if (wv > 0) {
#pragma unroll
        for (int r = 0; r < 4; ++r) {
            cmb[wv - 1][lg * 4 + r][0 * 16 + lr] = pv0[r];
            cmb[wv - 1][lg * 4 + r][1 * 16 + lr] = pv1[r];
            cmb[wv - 1][lg * 4 + r][2 * 16 + lr] = pv2[r];
            cmb[wv - 1][lg * 4 + r][3 * 16 + lr] = pv3[r];
        }
        if (lr == 0)
#pragma unroll
            for (int r = 0; r < 4; ++r) dcmb[wv - 1][lg * 4 + r] = den[r];
    }
    __syncthreads();
    if (wv == 0) {
        f32x4* pvp[4] = { &pv0, &pv1, &pv2, &pv3 };
#pragma unroll
        for (int r = 0; r < 4; ++r) {
            const int il = lg * 4 + r;
            const float dt = den[r] + dcmb[0][il] + dcmb[1][il] + dcmb[2][il];
            const float iv = __builtin_amdgcn_rcpf(dt);
            const size_t rowb = (size_t)(b * TT + rg * 16 + il) * CC + h * 64;
#pragma unroll
            for (int n = 0; n < 4; ++n) {
                const float val = ((*pvp[n])[r] + cmb[0][il][n * 16 + lr] +
                                   cmb[1][il][n * 16 + lr] + cmb[2][il][n * 16 + lr]) * iv;
                const ushort hb = f2bf(val);
                yh[rowb + n * 16 + lr] = hb;
                yl[rowb + n * 16 + lr] = f2bf(val - bf2f(hb));
            }
        }
    }
#undef TRANSF
#undef LOADG2
#undef MMG
}

// ---------------- output GEMM: out = y @ Wproj^T (pre-split A and B) ----------------
__global__ __launch_bounds__(256) void gemm_out(const ushort* __restrict__ Ahp,
                                                const ushort* __restrict__ Alp,
                                                const ushort* __restrict__ Wh,
                                                const ushort* __restrict__ Wl,
                                                float* __restrict__ C) {
    __shared__ ushort Ah[128 * 40], Al[128 * 40], Bh[128 * 40], Bl[128 * 40];
    const int tid = threadIdx.x, lane = tid & 63, wv = tid >> 6;
    const int wr = wv >> 1, wc = wv & 1, lr = lane & 15, lg = lane >> 4;
    const int m0 = blockIdx.y * 128, n0 = blockIdx.x * 128;
    const int srow = tid >> 1, sk0 = (tid & 1) * 16;
    const ushort* Ahq = Ahp + (size_t)(m0 + srow) * CC + sk0;
    const ushort* Alq = Alp + (size_t)(m0 + srow) * CC + sk0;
    const ushort* Bhp = Wh + (size_t)(n0 + srow) * CC + sk0;
    const ushort* Blp = Wl + (size_t)(n0 + srow) * CC + sk0;

    f32x4 acc[4][4] = {};
    bf16x8 ahv[2], alv[2], bhv[2], blv[2];
    ahv[0] = *(const bf16x8*)(Ahq);      ahv[1] = *(const bf16x8*)(Ahq + 8);
    alv[0] = *(const bf16x8*)(Alq);      alv[1] = *(const bf16x8*)(Alq + 8);
    bhv[0] = *(const bf16x8*)(Bhp);      bhv[1] = *(const bf16x8*)(Bhp + 8);
    blv[0] = *(const bf16x8*)(Blp);      blv[1] = *(const bf16x8*)(Blp + 8);

    for (int kk = 0; kk < CC; kk += 32) {
        __syncthreads();
        *(bf16x8*)&Ah[srow * 40 + sk0] = ahv[0];
        *(bf16x8*)&Ah[srow * 40 + sk0 + 8] = ahv[1];
        *(bf16x8*)&Al[srow * 40 + sk0] = alv[0];
        *(bf16x8*)&Al[srow * 40 + sk0 + 8] = alv[1];
        *(bf16x8*)&Bh[srow * 40 + sk0] = bhv[0];
        *(bf16x8*)&Bh[srow * 40 + sk0 + 8] = bhv[1];
        *(bf16x8*)&Bl[srow * 40 + sk0] = blv[0];
        *(bf16x8*)&Bl[srow * 40 + sk0 + 8] = blv[1];
        __syncthreads();
        if (kk + 32 < CC) {
            ahv[0] = *(const bf16x8*)(Ahq + kk + 32);
            ahv[1] = *(const bf16x8*)(Ahq + kk + 40);
            alv[0] = *(const bf16x8*)(Alq + kk + 32);
            alv[1] = *(const bf16x8*)(Alq + kk + 40);
            bhv[0] = *(const bf16x8*)(Bhp + kk + 32);
            bhv[1] = *(const bf16x8*)(Bhp + kk + 40);
            blv[0] = *(const bf16x8*)(Blp + kk + 32);
            blv[1] = *(const bf16x8*)(Blp + kk + 40);
        }
        bf16x8 a_h[4], a_l[4];
#pragma unroll
        for (int m = 0; m < 4; ++m) {
            const int off = (wr * 64 + m * 16 + lr) * 40 + lg * 8;
            a_h[m] = *(const bf16x8*)&Ah[off];
            a_l[m] = *(const bf16x8*)&Al[off];
        }
#pragma unroll
        for (int n = 0; n < 4; ++n) {
            const int off = (wc * 64 + n * 16 + lr) * 40 + lg * 8;
            bf16x8 b_h = *(const bf16x8*)&Bh[off];
            bf16x8 b_l = *(const bf16x8*)&Bl[off];
#pragma unroll
            for (int m = 0; m < 4; ++m) {
                acc[m][n] = MFMA(a_h[m], b_h, acc[m][n]);
                acc[m][n] = MFMA(a_h[m], b_l, acc[m][n]);
                acc[m][n] = MFMA(a_l[m], b_h, acc[m][n]);
            }
        }
    }
#pragma unroll
    for (int m = 0; m < 4; ++m)
#pragma unroll
        for (int n = 0; n < 4; ++n)
#pragma unroll
            for (int r = 0; r < 4; ++r)
                C[(size_t)(m0 + wr * 64 + m * 16 + lg * 4 + r) * CC + n0 + wc * 64 + n * 16 + lr] =
                    acc[m][n][r];
}

extern "C" void kernel_launch(void* const* d_in, const int* in_sizes, int n_in,
                              void* d_out, int out_size, void* d_ws, size_t ws_size,
                              hipStream_t stream) {
    const float* x     = (const float*)d_in[0];
    const float* Wqkv  = (const float*)d_in[1];
    const float* Wproj = (const float*)d_in[2];
    const float* kcurv = (const float*)d_in[3];
    float* out = (float*)d_out;

    const size_t PL = (size_t)4096 * CC;
    char* w = (char*)d_ws;
    const bool ps = ws_size >= 53870592ULL;

    ushort *xh, *xl, *qh, *ql, *kh, *kl, *vT, *Wqh, *Wql, *Wph, *Wpl, *yh, *yl;
    float *x2g, *y2g;
    if (ps) {
        xh = (ushort*)w;          xl = xh + PL;     // reused as yh/yl later
        qh = xl + PL;  ql = qh + PL;  kh = ql + PL;  kl = kh + PL;  vT = kl + PL;
        x2g = (float*)(vT + PL);  y2g = x2g + 48 * TT;
        Wqh = (ushort*)(y2g + 48 * TT);  Wql = Wqh + (size_t)2304 * CC;
        Wph = Wql + (size_t)2304 * CC;   Wpl = Wph + (size_t)CC * CC;
        yh = (ushort*)w;  yl = yh + PL;
    } else {
        Wqh = (ushort*)w;  Wql = Wqh + (size_t)2304 * CC;
        yh = (ushort*)w;   yl = yh + PL;
        qh = (ushort*)(w + 2 * PL * 2);
        ql = qh + PL;  kh = ql + PL;  kl = kh + PL;  vT = kl + PL;
        Wph = vT + PL;  Wpl = Wph + (size_t)CC * CC;
        x2g = (float*)(Wpl + (size_t)CC * CC);  y2g = x2g + 48 * TT;
        xh = xl = nullptr;
    }

    wprep<<<2304 * CC / 4 / 256, 256, 0, stream>>>(Wqkv, Wqh, Wql, 2304 * CC / 4);
    wprep<<<CC * CC / 4 / 256, 256, 0, stream>>>(Wproj, Wph, Wpl, CC * CC / 4);
    if (ps) {
        wprep<<<4096 * CC / 4 / 256, 256, 0, stream>>>(x, xh, xl, 4096 * CC / 4);
        gemm_qkv<true><<<dim3(18, 32), 256, 0, stream>>>(x, xh, xl, Wqh, Wql, kcurv,
                                                         qh, ql, kh, kl, vT, x2g, y2g);
    } else {
        gemm_qkv<false><<<dim3(18, 32), 256, 0, stream>>>(x, nullptr, nullptr, Wqh, Wql,
                                                          kcurv, qh, ql, kh, kl, vT, x2g, y2g);
    }
    hyp_attn<<<3072, 256, 0, stream>>>(qh, ql, kh, kl, vT, x2g, y2g, kcurv, yh, yl);
    gemm_out<<<dim3(6, 32), 256, 0, stream>>>(yh, yl, Wph, Wpl, out);
}